// Round 7
// baseline (152.085 us; speedup 1.0000x reference)
//
#include <hip/hip_runtime.h>

typedef unsigned short u16;
typedef unsigned int u32;
using frag8 = __attribute__((ext_vector_type(8))) short;  // 8 bf16 (4 VGPRs)
using f32x4 = __attribute__((ext_vector_type(4))) float;

#define MFMA(a, b, c) __builtin_amdgcn_mfma_f32_16x16x32_bf16(a, b, c, 0, 0, 0)

// fp32 -> bf16, round-to-nearest-even (finite inputs only)
__device__ __forceinline__ u16 f2bf(float f) {
  u32 x = __float_as_uint(f);
  x += 0x7fffu + ((x >> 16) & 1u);
  return (u16)(x >> 16);
}

// ---------------------------------------------------------------------------
// Pre-pass: qkv (4,1536,2048) fp32 ->
//   Qt[b][t][c] bf16 (scaled), Kt[b][s][c] bf16 (scaled), Vn[b][c][s] bf16
// Q,K pre-scaled by 64^-0.25 * sqrt(log2 e) so the flash kernel uses raw
// v_exp_f32.
// ---------------------------------------------------------------------------
__global__ __launch_bounds__(256) void qkv_prepass_kernel(
    const float* __restrict__ qkv, u16* __restrict__ Qt, u16* __restrict__ Kt,
    u16* __restrict__ Vn) {
  __shared__ float tile[64 * 65];
  const int id = blockIdx.x;
  const int tid = threadIdx.x;

  if (id < 2048) {
    const bool isK = id >= 1024;
    const int lid = isK ? (id - 1024) : id;
    const int b = lid >> 5;
    const int t0 = (lid & 31) * 64;
    const int bs = b >> 3, h = b & 7;
    const float* src =
        qkv + ((size_t)(bs * 1536 + h * 192 + (isK ? 64 : 0))) * 2048 + t0;
    u16* dst = (isK ? Kt : Qt) + ((size_t)b * 2048 + t0) * 64;
    const float scale = 0.42466090014400953f;  // 64^-0.25 * sqrt(log2 e)

    const int t4 = (tid & 15) * 4;
    const int c = tid >> 4;
#pragma unroll
    for (int i = 0; i < 4; ++i) {
      int cc = c + 16 * i;
      float4 f = *reinterpret_cast<const float4*>(src + (size_t)cc * 2048 + t4);
      tile[cc * 65 + t4 + 0] = f.x * scale;
      tile[cc * 65 + t4 + 1] = f.y * scale;
      tile[cc * 65 + t4 + 2] = f.z * scale;
      tile[cc * 65 + t4 + 3] = f.w * scale;
    }
    __syncthreads();
    const int c0 = (tid & 7) * 8;
#pragma unroll
    for (int p = 0; p < 2; ++p) {
      int tr = (tid >> 3) + 32 * p;
      u32 pk[4];
#pragma unroll
      for (int uu = 0; uu < 4; ++uu) {
        u16 lo = f2bf(tile[(c0 + 2 * uu) * 65 + tr]);
        u16 hi = f2bf(tile[(c0 + 2 * uu + 1) * 65 + tr]);
        pk[uu] = (u32)lo | ((u32)hi << 16);
      }
      *reinterpret_cast<uint4*>(dst + (size_t)tr * 64 + c0) =
          make_uint4(pk[0], pk[1], pk[2], pk[3]);
    }
  } else {
    const size_t base = (size_t)(id - 2048) * 4096;
#pragma unroll
    for (int it = 0; it < 2; ++it) {
      size_t vi = base + (size_t)it * 2048 + (size_t)tid * 8;
      int b = (int)(vi >> 17);
      int r = (int)(vi & 131071);
      int bs = b >> 3, h = b & 7;
      const float* sp = qkv + ((size_t)(bs * 1536 + h * 192 + 128)) * 2048 + r;
      float4 f0 = *reinterpret_cast<const float4*>(sp);
      float4 f1 = *reinterpret_cast<const float4*>(sp + 4);
      uint4 pk;
      pk.x = (u32)f2bf(f0.x) | ((u32)f2bf(f0.y) << 16);
      pk.y = (u32)f2bf(f0.z) | ((u32)f2bf(f0.w) << 16);
      pk.z = (u32)f2bf(f1.x) | ((u32)f2bf(f1.y) << 16);
      pk.w = (u32)f2bf(f1.z) | ((u32)f2bf(f1.w) << 16);
      *reinterpret_cast<uint4*>(Vn + vi) = pk;
    }
  }
}

// ---------------------------------------------------------------------------
// Flash attention, BARRIER-FREE streaming form. One wave per block (64 thr),
// 64 t-columns per wave, grid 1024 = 32 heads x 32 q-tiles (XCD-swizzled).
// K/V MFMA fragments are loaded DIRECTLY global->VGPR (L2-resident per XCD;
// 16B/lane, 64B-contiguous per s-row) with a one-tile register double buffer
// -> no LDS staging, no __syncthreads in the loop, waves fully independent.
// LDS holds only the 8 KiB wave-private Q/P overlay (XOR-swizzled rows).
// VGPR budget: __launch_bounds__(64,1) -> up to 512 unified VGPR+AGPR.
// ---------------------------------------------------------------------------
#define STAGEQ(dstOff, srcPtr)                                             \
  __builtin_amdgcn_global_load_lds(                                        \
      (const __attribute__((address_space(1))) void*)(srcPtr),             \
      (__attribute__((address_space(3))) void*)(qp + (dstOff) + tid * 8),  \
      16, 0, 0)

// K-frag (i=s-chunk, h=c-half): lane holds A[m = i*16+s16][k = h*32+q*8 ..+8]
#define LDK(DST, KP)                                                       \
  _Pragma("unroll") for (int i = 0; i < 4; ++i) {                          \
    DST[i][0] = *(const frag8*)((KP) + i * 1024);                          \
    DST[i][1] = *(const frag8*)((KP) + i * 1024 + 32);                     \
  }

// V-frag (i=c-chunk, h=s-half): lane holds A[m = i*16+s16][k = h*32+q*8 ..+8]
#define LDV(DST, VP)                                                       \
  _Pragma("unroll") for (int i = 0; i < 4; ++i) {                          \
    DST[i][0] = *(const frag8*)((VP) + i * 32768);                         \
    DST[i][1] = *(const frag8*)((VP) + i * 32768 + 32);                    \
  }

// body: PRE = prefetch loads for next tile (registers, deep vmcnt);
// S_k (MFMA, frags in regs) -> exp/P-write (LDS) -> P-read -> PV_k. No sync.
#define BODY(KF, VF, PRE)                                                  \
  {                                                                        \
    PRE                                                                    \
    f32x4 S[4][4];                                                         \
    _Pragma("unroll") for (int i = 0; i < 4; ++i) {                        \
      _Pragma("unroll") for (int j = 0; j < 4; ++j) {                      \
        f32x4 z = {0.f, 0.f, 0.f, 0.f};                                    \
        z = MFMA(KF[i][0], aQ0[j], z);                                     \
        z = MFMA(KF[i][1], aQ1[j], z);                                     \
        S[i][j] = z;                                                       \
      }                                                                    \
    }                                                                      \
    _Pragma("unroll") for (int j = 0; j < 4; ++j) {                        \
      _Pragma("unroll") for (int i = 0; i < 4; ++i) {                      \
        float p0 = __builtin_amdgcn_exp2f(S[i][j][0]);                     \
        float p1 = __builtin_amdgcn_exp2f(S[i][j][1]);                     \
        float p2 = __builtin_amdgcn_exp2f(S[i][j][2]);                     \
        float p3 = __builtin_amdgcn_exp2f(S[i][j][3]);                     \
        lp[j] += (p0 + p1) + (p2 + p3);                                    \
        u32 a0 = __float_as_uint(p0) + 0x8000u;                            \
        u32 a1 = __float_as_uint(p1) + 0x8000u;                            \
        u32 a2 = __float_as_uint(p2) + 0x8000u;                            \
        u32 a3 = __float_as_uint(p3) + 0x8000u;                            \
        *(uint2*)(pwb + j * 1024 + pslot[i]) =                             \
            make_uint2(__builtin_amdgcn_perm(a1, a0, 0x07060302u),         \
                       __builtin_amdgcn_perm(a3, a2, 0x07060302u));        \
      }                                                                    \
    }                                                                      \
    asm volatile("" ::: "memory"); /* P-writes ordered before P-reads */   \
    frag8 pf0[4], pf1[4];                                                  \
    _Pragma("unroll") for (int j = 0; j < 4; ++j) {                        \
      pf0[j] = *(const frag8*)(pqb + j * 1024 + off0);                     \
      pf1[j] = *(const frag8*)(pqb + j * 1024 + off1);                     \
    }                                                                      \
    _Pragma("unroll") for (int i = 0; i < 4; ++i) {                        \
      _Pragma("unroll") for (int j = 0; j < 4; ++j) {                      \
        o[i][j] = MFMA(VF[i][0], pf0[j], o[i][j]);                         \
        o[i][j] = MFMA(VF[i][1], pf1[j], o[i][j]);                         \
      }                                                                    \
    }                                                                      \
  }

__global__ __launch_bounds__(64, 1) void attn_flash_kernel(
    const u16* __restrict__ Qt, const u16* __restrict__ Kt,
    const u16* __restrict__ Vn, float* __restrict__ out) {
  __shared__ __align__(16) u16 qp[4096];  // 64 rows x 64 u16, XOR-swizzled

  // XCD swizzle: blk&7 = XCD; 4 heads per XCD (K+V = 3 MB, L2-resident)
  const int blk = blockIdx.x;
  const int ii = blk >> 3;
  const int b = ((blk & 7) << 2) + (ii >> 5);  // head 0..31
  const int qt = ii & 31;                      // q-tile (64 t each)

  const int tid = threadIdx.x;  // 0..63, one wave
  const int s16 = tid & 15, q = tid >> 4;
  const int x = s16 & 7;

  const u16* Qg = Qt + ((size_t)b * 2048 + qt * 64) * 64;
  const u16* Kg = Kt + (size_t)b * 2048 * 64;
  const u16* Vg = Vn + (size_t)b * 64 * 2048;

  // per-lane fragment base offsets (u16 units)
  const u16* kgl = Kg + s16 * 64 + q * 8;    // + kt*4096 + i*1024 + h*32
  const u16* vgl = Vg + s16 * 2048 + q * 8;  // + kt*64 + i*32768 + h*32

  // Q staging (wave-private): 8 ops x 1 KiB, XOR swizzle on the source side
  const int srow = tid >> 3;  // 0..7
  const int qoff = srow * 64 + ((tid & 7) ^ (srow & 7)) * 8;
#pragma unroll
  for (int n = 0; n < 8; ++n) STAGEQ(n * 512, Qg + qoff + n * 512);

  // frag read offsets into the swizzled Q/P rows
  const u16* pqb = qp + s16 * 64;  // row t=s16 (+j*1024 per 16-t chunk)
  u16* pwb = (u16*)pqb;
  const int off0 = (q ^ x) * 8;        // k-groups q   (k 0..31)
  const int off1 = ((q + 4) ^ x) * 8;  // k-groups q+4 (k 32..63)
  int pslot[4];
#pragma unroll
  for (int i = 0; i < 4; ++i)
    pslot[i] = ((2 * i + (q >> 1)) ^ x) * 8 + (q & 1) * 4;

  // prefetch tile 0 K/V fragments straight into registers
  frag8 kfA[4][2], kfB[4][2], vfA[4][2], vfB[4][2];
  LDK(kfA, kgl)
  LDV(vfA, vgl)

  __syncthreads();  // single wave: just drains the Q global_load_lds

  // loop-invariant Q fragments; qp region is then reused for P (in-order DS)
  frag8 aQ0[4], aQ1[4];
#pragma unroll
  for (int j = 0; j < 4; ++j) {
    aQ0[j] = *(const frag8*)(pqb + j * 1024 + off0);
    aQ1[j] = *(const frag8*)(pqb + j * 1024 + off1);
  }

  f32x4 o[4][4];
#pragma unroll
  for (int i = 0; i < 4; ++i)
#pragma unroll
    for (int j = 0; j < 4; ++j) o[i][j] = (f32x4){0.f, 0.f, 0.f, 0.f};
  float lp[4] = {0.f, 0.f, 0.f, 0.f};

  for (int kt = 0; kt < 30; kt += 2) {
    BODY(kfA, vfA, LDK(kfB, kgl + (size_t)(kt + 1) * 4096)
                       LDV(vfB, vgl + (kt + 1) * 64))
    BODY(kfB, vfB, LDK(kfA, kgl + (size_t)(kt + 2) * 4096)
                       LDV(vfA, vgl + (kt + 2) * 64))
  }
  BODY(kfA, vfA, LDK(kfB, kgl + (size_t)31 * 4096) LDV(vfB, vgl + 31 * 64))
  BODY(kfB, vfB, )

  // softmax denominators: cross-quad reduce (lanes share t = s16)
  float rl[4];
#pragma unroll
  for (int j = 0; j < 4; ++j) {
    lp[j] += __shfl_xor(lp[j], 16);
    lp[j] += __shfl_xor(lp[j], 32);
    rl[j] = 1.0f / lp[j];
  }

  // lane holds O^T[c = i*16 + q*4 + r][t = qt*64 + 16j + s16]
  float* ob = out + (size_t)(b * 64 + q * 4) * 2048 + qt * 64 + s16;
#pragma unroll
  for (int i = 0; i < 4; ++i)
#pragma unroll
    for (int j = 0; j < 4; ++j)
#pragma unroll
      for (int r = 0; r < 4; ++r)
        ob[(size_t)(i * 16 + r) * 2048 + j * 16] = o[i][j][r] * rl[j];
}

extern "C" void kernel_launch(void* const* d_in, const int* in_sizes, int n_in,
                              void* d_out, int out_size, void* d_ws,
                              size_t ws_size, hipStream_t stream) {
  const float* qkv = (const float*)d_in[0];
  float* out = (float*)d_out;
  u16* Qt = (u16*)d_ws;
  u16* Kt = Qt + (size_t)32 * 2048 * 64;
  u16* Vn = Kt + (size_t)32 * 2048 * 64;

  qkv_prepass_kernel<<<3072, 256, 0, stream>>>(qkv, Qt, Kt, Vn);
  attn_flash_kernel<<<1024, 64, 0, stream>>>(Qt, Kt, Vn, out);
}

// Round 8
// 131.306 us; speedup vs baseline: 1.1583x; 1.1583x over previous
//
#include <hip/hip_runtime.h>

typedef unsigned short u16;
typedef unsigned int u32;
using frag8 = __attribute__((ext_vector_type(8))) short;  // 8 bf16 (4 VGPRs)
using f32x4 = __attribute__((ext_vector_type(4))) float;

#define MFMA(a, b, c) __builtin_amdgcn_mfma_f32_16x16x32_bf16(a, b, c, 0, 0, 0)

// fp32 -> bf16, round-to-nearest-even (finite inputs only)
__device__ __forceinline__ u16 f2bf(float f) {
  u32 x = __float_as_uint(f);
  x += 0x7fffu + ((x >> 16) & 1u);
  return (u16)(x >> 16);
}

// ---------------------------------------------------------------------------
// Pre-pass: qkv (4,1536,2048) fp32 ->
//   Qt[b][t][c] bf16 (scaled), Kt[b][s][c] bf16 (scaled), Vn[b][c][s] bf16
// Q,K pre-scaled by 64^-0.25 * sqrt(log2 e) so the flash kernel uses raw
// v_exp_f32.
// ---------------------------------------------------------------------------
__global__ __launch_bounds__(256) void qkv_prepass_kernel(
    const float* __restrict__ qkv, u16* __restrict__ Qt, u16* __restrict__ Kt,
    u16* __restrict__ Vn) {
  __shared__ float tile[64 * 65];
  const int id = blockIdx.x;
  const int tid = threadIdx.x;

  if (id < 2048) {
    const bool isK = id >= 1024;
    const int lid = isK ? (id - 1024) : id;
    const int b = lid >> 5;
    const int t0 = (lid & 31) * 64;
    const int bs = b >> 3, h = b & 7;
    const float* src =
        qkv + ((size_t)(bs * 1536 + h * 192 + (isK ? 64 : 0))) * 2048 + t0;
    u16* dst = (isK ? Kt : Qt) + ((size_t)b * 2048 + t0) * 64;
    const float scale = 0.42466090014400953f;  // 64^-0.25 * sqrt(log2 e)

    const int t4 = (tid & 15) * 4;
    const int c = tid >> 4;
#pragma unroll
    for (int i = 0; i < 4; ++i) {
      int cc = c + 16 * i;
      float4 f = *reinterpret_cast<const float4*>(src + (size_t)cc * 2048 + t4);
      tile[cc * 65 + t4 + 0] = f.x * scale;
      tile[cc * 65 + t4 + 1] = f.y * scale;
      tile[cc * 65 + t4 + 2] = f.z * scale;
      tile[cc * 65 + t4 + 3] = f.w * scale;
    }
    __syncthreads();
    const int c0 = (tid & 7) * 8;
#pragma unroll
    for (int p = 0; p < 2; ++p) {
      int tr = (tid >> 3) + 32 * p;
      u32 pk[4];
#pragma unroll
      for (int uu = 0; uu < 4; ++uu) {
        u16 lo = f2bf(tile[(c0 + 2 * uu) * 65 + tr]);
        u16 hi = f2bf(tile[(c0 + 2 * uu + 1) * 65 + tr]);
        pk[uu] = (u32)lo | ((u32)hi << 16);
      }
      *reinterpret_cast<uint4*>(dst + (size_t)tr * 64 + c0) =
          make_uint4(pk[0], pk[1], pk[2], pk[3]);
    }
  } else {
    const size_t base = (size_t)(id - 2048) * 4096;
#pragma unroll
    for (int it = 0; it < 2; ++it) {
      size_t vi = base + (size_t)it * 2048 + (size_t)tid * 8;
      int b = (int)(vi >> 17);
      int r = (int)(vi & 131071);
      int bs = b >> 3, h = b & 7;
      const float* sp = qkv + ((size_t)(bs * 1536 + h * 192 + 128)) * 2048 + r;
      float4 f0 = *reinterpret_cast<const float4*>(sp);
      float4 f1 = *reinterpret_cast<const float4*>(sp + 4);
      uint4 pk;
      pk.x = (u32)f2bf(f0.x) | ((u32)f2bf(f0.y) << 16);
      pk.y = (u32)f2bf(f0.z) | ((u32)f2bf(f0.w) << 16);
      pk.z = (u32)f2bf(f1.x) | ((u32)f2bf(f1.y) << 16);
      pk.w = (u32)f2bf(f1.z) | ((u32)f2bf(f1.w) << 16);
      *reinterpret_cast<uint4*>(Vn + vi) = pk;
    }
  }
}

// ---------------------------------------------------------------------------
// Flash attention, S^T form, no-max softmax, S-SPLIT:
// block = 4 waves = 2 t-groups (64 t) x 2 s-halves (16 tiles each).
// Grid 512 (XCD-swizzled) -> 2 blocks/CU = 8 waves/CU (latency hiding, the
// R6/R7 failure) AND W=64 t/wave (each K/V frag read feeds 4 MFMAs, halving
// LDS-read traffic per output vs R5 — the LDS pipe is the binding resource).
// No-max softmax is linear in s: halves accumulate (O_unnorm, l) and combine.
// LDS (u16 units, 64 KiB total):
//   [0,4096)      Q tg0 -> P of wave (tg0,sh0)
//   [4096,8192)   Q tg1 -> P of wave (tg1,sh0)
//   [8192,12288)  P of (tg0,sh1)      [12288,16384) P of (tg1,sh1)
//   [16384,20480) K stream sh0        [20480,24576) K stream sh1
//   [24576,28672) V stream sh0        [28672,32768) V stream sh1
// Single-buffered tiles, two barriers/step: frag-reads -> sync -> async stage
// next tiles (hidden under S/exp/PV compute) -> sync.
// ---------------------------------------------------------------------------
#define STAGE(dstOff, srcPtr)                                                  \
  __builtin_amdgcn_global_load_lds(                                            \
      (const __attribute__((address_space(1))) void*)(srcPtr),                 \
      (__attribute__((address_space(3))) void*)(ldsbase + (dstOff) + tid * 8), \
      16, 0, 0)

// stage K tiles N (stream0) and N+16 (stream1), V likewise
#define STG_STEP(N)                                                         \
  STAGE(16384, Kg + (size_t)(N) * 4096 + koff0);                            \
  STAGE(16384 + 2048, Kg + (size_t)(N) * 4096 + koff0 + 2048);              \
  STAGE(20480, Kg + (size_t)((N) + 16) * 4096 + koff0);                     \
  STAGE(20480 + 2048, Kg + (size_t)((N) + 16) * 4096 + koff0 + 2048);       \
  STAGE(24576, Vg + (size_t)(N) * 64 + voff0);                              \
  STAGE(24576 + 2048, Vg + (size_t)(N) * 64 + voff0 + 65536);               \
  STAGE(28672, Vg + (size_t)((N) + 16) * 64 + voff0);                       \
  STAGE(28672 + 2048, Vg + (size_t)((N) + 16) * 64 + voff0 + 65536);

// step: read K/V frags of current tile -> barrier -> stage next (async) ->
// S MFMA -> exp/P-write -> P-read -> PV MFMA -> barrier (staging drained)
#define BODY(STG)                                                           \
  {                                                                         \
    frag8 kf0[4], kf1[4], vf0[4], vf1[4];                                   \
    _Pragma("unroll") for (int i = 0; i < 4; ++i) {                         \
      kf0[i] = *(const frag8*)(kBa + i * 1024);                             \
      kf1[i] = *(const frag8*)(kBb + i * 1024);                             \
      vf0[i] = *(const frag8*)(vBa + i * 1024);                             \
      vf1[i] = *(const frag8*)(vBb + i * 1024);                             \
    }                                                                       \
    __syncthreads(); /* all waves done reading the single buffers */        \
    STG                                                                     \
    f32x4 S[4][4];                                                          \
    _Pragma("unroll") for (int i = 0; i < 4; ++i) {                         \
      _Pragma("unroll") for (int j = 0; j < 4; ++j) {                       \
        f32x4 z = {0.f, 0.f, 0.f, 0.f};                                     \
        z = MFMA(kf0[i], aQ0[j], z);                                        \
        z = MFMA(kf1[i], aQ1[j], z);                                        \
        S[i][j] = z;                                                        \
      }                                                                     \
    }                                                                       \
    _Pragma("unroll") for (int j = 0; j < 4; ++j) {                         \
      _Pragma("unroll") for (int i = 0; i < 4; ++i) {                       \
        float p0 = __builtin_amdgcn_exp2f(S[i][j][0]);                      \
        float p1 = __builtin_amdgcn_exp2f(S[i][j][1]);                      \
        float p2 = __builtin_amdgcn_exp2f(S[i][j][2]);                      \
        float p3 = __builtin_amdgcn_exp2f(S[i][j][3]);                      \
        lp[j] += (p0 + p1) + (p2 + p3);                                     \
        u32 a0 = __float_as_uint(p0) + 0x8000u;                             \
        u32 a1 = __float_as_uint(p1) + 0x8000u;                             \
        u32 a2 = __float_as_uint(p2) + 0x8000u;                             \
        u32 a3 = __float_as_uint(p3) + 0x8000u;                             \
        *(uint2*)(pPb + j * 1024 + pslot[i]) =                              \
            make_uint2(__builtin_amdgcn_perm(a1, a0, 0x07060302u),          \
                       __builtin_amdgcn_perm(a3, a2, 0x07060302u));         \
      }                                                                     \
    }                                                                       \
    asm volatile("" ::: "memory"); /* P-writes ordered before P-reads */    \
    {                                                                       \
      frag8 pf0[4], pf1[4];                                                 \
      _Pragma("unroll") for (int j = 0; j < 4; ++j) {                       \
        pf0[j] = *(const frag8*)(pPb + j * 1024 + off0);                    \
        pf1[j] = *(const frag8*)(pPb + j * 1024 + off1);                    \
      }                                                                     \
      _Pragma("unroll") for (int i = 0; i < 4; ++i) {                       \
        _Pragma("unroll") for (int j = 0; j < 4; ++j) {                     \
          o[i][j] = MFMA(vf0[i], pf0[j], o[i][j]);                          \
          o[i][j] = MFMA(vf1[i], pf1[j], o[i][j]);                          \
        }                                                                   \
      }                                                                     \
    }                                                                       \
    __syncthreads(); /* staging complete (vmcnt drained) */                 \
  }

__global__ __launch_bounds__(256, 2) void attn_flash_kernel(
    const u16* __restrict__ Qt, const u16* __restrict__ Kt,
    const u16* __restrict__ Vn, float* __restrict__ out) {
  __shared__ __align__(16) unsigned char smem[65536];
  u16* ldsbase = (u16*)smem;

  // XCD swizzle: blk&7 = XCD; 4 heads per XCD (K+V L2-resident per XCD)
  const int blk = blockIdx.x;
  const int ii = blk >> 3;
  const int b = ((blk & 7) << 2) + (ii >> 4);  // head 0..31
  const int qt = ii & 15;                      // q-tile (128 t each)

  const int tid = threadIdx.x;
  const int w = tid >> 6;
  const int tg = w & 1;   // t-group: t in [64*tg, 64*tg+64) of the q-tile
  const int sh = w >> 1;  // s-half: tiles [16*sh, 16*sh+16)
  const int lane = tid & 63;
  const int s16 = lane & 15, q = lane >> 4;
  const int x = s16 & 7;

  const u16* Qg = Qt + ((size_t)b * 2048 + qt * 128) * 64;
  const u16* Kg = Kt + (size_t)b * 2048 * 64;
  const u16* Vg = Vn + (size_t)b * 64 * 2048;

  // staging lane offsets (u16 units)
  const int srow = tid >> 3;
  const int sgl = (tid & 7) ^ (srow & 7);
  const int koff0 = srow * 64 + sgl * 8;    // pitch-64 tiles (Q,K)
  const int voff0 = srow * 2048 + sgl * 8;  // pitch-2048 (V)

  // fragment read bases for this wave's s-stream (XOR-swizzled)
  const u16* kBa = ldsbase + 16384 + sh * 4096 + s16 * 64 + ((q ^ x) * 8);
  const u16* kBb = ldsbase + 16384 + sh * 4096 + s16 * 64 + (((q + 4) ^ x) * 8);
  const u16* vBa = ldsbase + 24576 + sh * 4096 + s16 * 64 + ((q ^ x) * 8);
  const u16* vBb = ldsbase + 24576 + sh * 4096 + s16 * 64 + (((q + 4) ^ x) * 8);
  // Q rows of this t-group; P region private to this (tg,sh) wave
  const u16* pqb = ldsbase + tg * 4096 + s16 * 64;
  u16* pPb = ldsbase + tg * 4096 + sh * 8192 + s16 * 64;
  const int off0 = (q ^ x) * 8;
  const int off1 = ((q + 4) ^ x) * 8;
  int pslot[4];
#pragma unroll
  for (int i = 0; i < 4; ++i)
    pslot[i] = ((2 * i + (q >> 1)) ^ x) * 8 + (q & 1) * 4;

  // prologue: stage Q (128x64, 4 calls) + K/V tiles {0,16}
  STAGE(0, Qg + koff0);
  STAGE(2048, Qg + koff0 + 2048);
  STAGE(4096, Qg + koff0 + 4096);
  STAGE(6144, Qg + koff0 + 6144);
  STG_STEP(0)
  __syncthreads();

  // loop-invariant Q fragments (both s-half waves read the shared Q rows)
  frag8 aQ0[4], aQ1[4];
#pragma unroll
  for (int j = 0; j < 4; ++j) {
    aQ0[j] = *(const frag8*)(pqb + j * 1024 + off0);
    aQ1[j] = *(const frag8*)(pqb + j * 1024 + off1);
  }
  __syncthreads();  // Q consumed by all before sh=0 overwrites it with P

  f32x4 o[4][4];
#pragma unroll
  for (int i = 0; i < 4; ++i)
#pragma unroll
    for (int j = 0; j < 4; ++j) o[i][j] = (f32x4){0.f, 0.f, 0.f, 0.f};
  float lp[4] = {0.f, 0.f, 0.f, 0.f};

  for (int n = 0; n < 15; ++n) {
    BODY(STG_STEP(n + 1))
  }
  BODY()  // tile 15 / 31, nothing left to stage

  // per-wave denominators (sum over this wave's s-range)
#pragma unroll
  for (int j = 0; j < 4; ++j) {
    lp[j] += __shfl_xor(lp[j], 16);
    lp[j] += __shfl_xor(lp[j], 32);
  }

  // combine s-halves through LDS (K/V + P regions are free now)
  if (sh == 1) {
    float* ow = (float*)(ldsbase + 16384) + tg * 4096 + lane * 64;
#pragma unroll
    for (int i = 0; i < 4; ++i)
#pragma unroll
      for (int j = 0; j < 4; ++j) *(f32x4*)(ow + (i * 4 + j) * 4) = o[i][j];
    float* lw = (float*)(ldsbase + 8192) + tg * 256 + lane * 4;
#pragma unroll
    for (int j = 0; j < 4; ++j) lw[j] = lp[j];
  }
  __syncthreads();
  if (sh == 0) {
    const float* ow = (const float*)(ldsbase + 16384) + tg * 4096 + lane * 64;
    const float* lw = (const float*)(ldsbase + 8192) + tg * 256 + lane * 4;
    float rl[4];
#pragma unroll
    for (int j = 0; j < 4; ++j) rl[j] = 1.0f / (lp[j] + lw[j]);
    // lane stores O^T[c = i*16+q*4+r][t = qt*128 + tg*64 + 16j + s16]
    float* ob =
        out + (size_t)(b * 64 + q * 4) * 2048 + qt * 128 + tg * 64 + s16;
#pragma unroll
    for (int i = 0; i < 4; ++i)
#pragma unroll
      for (int j = 0; j < 4; ++j) {
        f32x4 oo = *(const f32x4*)(ow + (i * 4 + j) * 4);
#pragma unroll
        for (int r = 0; r < 4; ++r)
          ob[(size_t)(i * 16 + r) * 2048 + j * 16] =
              (o[i][j][r] + oo[r]) * rl[j];
      }
  }
}

extern "C" void kernel_launch(void* const* d_in, const int* in_sizes, int n_in,
                              void* d_out, int out_size, void* d_ws,
                              size_t ws_size, hipStream_t stream) {
  const float* qkv = (const float*)d_in[0];
  float* out = (float*)d_out;
  u16* Qt = (u16*)d_ws;
  u16* Kt = Qt + (size_t)32 * 2048 * 64;
  u16* Vn = Kt + (size_t)32 * 2048 * 64;

  qkv_prepass_kernel<<<3072, 256, 0, stream>>>(qkv, Qt, Kt, Vn);
  attn_flash_kernel<<<512, 256, 0, stream>>>(Qt, Kt, Vn, out);
}